// Round 8
// baseline (442.921 us; speedup 1.0000x reference)
//
#include <hip/hip_runtime.h>

#define NN 50000
#define NE 800000
#define NH 64
#define NG 500
#define NPAD 50176   // 196*256
#define NBKT 782     // ceil(NN/64) 64-node buckets

// fp32 -> bf16 round-to-nearest-even
__device__ __forceinline__ unsigned short f2bf(float f) {
  unsigned x = __float_as_uint(f);
  unsigned r = ((x >> 16) & 1u) + 0x7fffu;
  return (unsigned short)((x + r) >> 16);
}
__device__ __forceinline__ float bf2f(unsigned short u) {
  return __uint_as_float(((unsigned)u) << 16);
}

// ---------------- per-bucket histogram (LDS-aggregated) ----------------

__global__ __launch_bounds__(256) void k_bhist(const int* __restrict__ dst, int* __restrict__ bcnt) {
  __shared__ int hist[NBKT];
  int t = threadIdx.x;
  for (int b = t; b < NBKT; b += 256) hist[b] = 0;
  __syncthreads();
  int e0 = blockIdx.x * 8192;
#pragma unroll
  for (int i = 0; i < 32; i++) {
    int e = e0 + i * 256 + t;
    if (e < NE) atomicAdd(&hist[dst[e] >> 6], 1);
  }
  __syncthreads();
  for (int b = t; b < NBKT; b += 256) {
    int c = hist[b];
    if (c) atomicAdd(&bcnt[b], c);
  }
}

// ---------------- bucket exclusive scan (single block, 4 elems/thread) ----------------

__global__ __launch_bounds__(256) void k_bscan(const int* __restrict__ bcnt, int* __restrict__ bptr,
                                               int* __restrict__ bcur) {
  __shared__ int s[256];
  int t = threadIdx.x;
  int base = t * 4;
  int v0 = (base + 0 < NBKT) ? bcnt[base + 0] : 0;
  int v1 = (base + 1 < NBKT) ? bcnt[base + 1] : 0;
  int v2 = (base + 2 < NBKT) ? bcnt[base + 2] : 0;
  int v3 = (base + 3 < NBKT) ? bcnt[base + 3] : 0;
  int lsum = v0 + v1 + v2 + v3;
  s[t] = lsum;
  __syncthreads();
#pragma unroll
  for (int off = 1; off < 256; off <<= 1) {
    int x = (t >= off) ? s[t - off] : 0;
    __syncthreads();
    s[t] += x;
    __syncthreads();
  }
  int pre = s[t] - lsum;
  int p0 = pre, p1 = pre + v0, p2 = p1 + v1, p3 = p2 + v2;
  if (base + 0 < NBKT) { bptr[base + 0] = p0; bcur[base + 0] = p0; }
  if (base + 1 < NBKT) { bptr[base + 1] = p1; bcur[base + 1] = p1; }
  if (base + 2 < NBKT) { bptr[base + 2] = p2; bcur[base + 2] = p2; }
  if (base + 3 < NBKT) { bptr[base + 3] = p3; bcur[base + 3] = p3; }
  if (t == 255) bptr[NBKT] = s[255];  // == NE
}

// ---------------- binning: colp[] = packed edges grouped by 64-node dst bucket ----------------

__global__ __launch_bounds__(256) void k_bin(const int* __restrict__ src, const int* __restrict__ dst,
                                             int* __restrict__ bcur, int* __restrict__ colp) {
  __shared__ int hist[NBKT];
  __shared__ int gbase[NBKT];
  int t = threadIdx.x;
  for (int b = t; b < NBKT; b += 256) hist[b] = 0;
  __syncthreads();
  int e0 = blockIdx.x * 8192;
#pragma unroll
  for (int i = 0; i < 32; i++) {
    int e = e0 + i * 256 + t;
    if (e < NE) atomicAdd(&hist[dst[e] >> 6], 1);
  }
  __syncthreads();
  for (int b = t; b < NBKT; b += 256) {
    int c = hist[b];
    gbase[b] = c ? atomicAdd(&bcur[b], c) : 0;
    hist[b] = 0;  // reuse as rank counter
  }
  __syncthreads();
#pragma unroll
  for (int i = 0; i < 32; i++) {
    int e = e0 + i * 256 + t;
    if (e < NE) {
      int s = src[e], d = dst[e];
      int b = d >> 6;
      int r = atomicAdd(&hist[b], 1);
      colp[gbase[b] + r] = (s << 6) | (d & 63);
    }
  }
}

// ---------------- bucket-local sort to exact CSR + deg/dinv/rowptr ----------------

__global__ __launch_bounds__(256) void k_csr(const int* __restrict__ bptr, const int* __restrict__ colp,
                                             int* __restrict__ cols, float* __restrict__ dinv,
                                             int* __restrict__ rowptr) {
  __shared__ int hist[64];
  __shared__ int excl[65];
  int t = threadIdx.x;
  int b = blockIdx.x;
  int st = bptr[b], en = bptr[b + 1];
  if (t < 64) hist[t] = 0;
  __syncthreads();
  for (int e = st + t; e < en; e += 256) atomicAdd(&hist[colp[e] & 63], 1);
  __syncthreads();
  if (t == 0) {
    int run = 0;
#pragma unroll
    for (int i = 0; i < 64; i++) { excl[i] = run; run += hist[i]; }
    excl[64] = run;
  }
  __syncthreads();
  if (t < 64) {
    int n = b * 64 + t;
    rowptr[n] = st + excl[t];
    if (n < NN) dinv[n] = rsqrtf((float)(hist[t] + 1));  // +1 self-loop
    hist[t] = 0;  // reuse as cursor
  }
  if (b == NBKT - 1 && t == 64) rowptr[NBKT * 64] = en;  // == NE
  __syncthreads();
  for (int e = st + t; e < en; e += 256) {
    int w = colp[e];
    int d = w & 63;
    int r = atomicAdd(&hist[d], 1);
    cols[st + excl[d] + r] = w >> 6;
  }
}

// ---------------- graph segment pointers from sorted batch (no atomics) ----------------

__global__ __launch_bounds__(256) void k_gptr(const int* __restrict__ batch, int* __restrict__ gptr) {
  int i = blockIdx.x * 256 + threadIdx.x;
  if (i >= NN) return;
  int bi = batch[i];
  int bp = (i > 0) ? batch[i - 1] : -1;
  for (int g = bp + 1; g <= bi; g++) gptr[g] = i;
  if (i == NN - 1) {
    for (int g = bi + 1; g <= NG; g++) gptr[g] = NN;
  }
}

// ---------------- encoder: X0 = [x|pos] @ enc_W + enc_b ----------------

__global__ __launch_bounds__(256) void k_encoder(const float* __restrict__ x, const float* __restrict__ pos,
                                                 const float* __restrict__ W, const float* __restrict__ b,
                                                 float* __restrict__ X0) {
  __shared__ float Ws[16 * 64];
  __shared__ float bs[64];
  int t = threadIdx.x;
  for (int i = t; i < 1024; i += 256) Ws[i] = W[i];
  if (t < 64) bs[t] = b[t];
  __syncthreads();
  int n = blockIdx.x * 4 + (t >> 6);
  int h = t & 63;
  if (n >= NN) return;
  float acc = bs[h];
#pragma unroll
  for (int f = 0; f < 14; f++) acc += x[n * 14 + f] * Ws[f * 64 + h];
  acc += pos[n * 2 + 0] * Ws[14 * 64 + h];
  acc += pos[n * 2 + 1] * Ws[15 * 64 + h];
  X0[n * 64 + h] = acc;
}

// ---------------- fused dual GEMM + epilogue (64-node tile, 48 KB LDS -> 3 blocks/CU) ----------------
// hW planes (bf16, column-split): plane0 = h in [0,32), plane1 = h in [32,64).
// agg = relu?(X) @ res_W + res_b + conv_b + dinv[n] * hWs[n]   (self-loop folded in)

__global__ __launch_bounds__(256) void k_gemm_dual(const float* __restrict__ Xin,
                                                   const float* __restrict__ Wc, const float* __restrict__ Wr,
                                                   const float* __restrict__ cb, const float* __restrict__ rb,
                                                   const float* __restrict__ dinv,
                                                   unsigned short* __restrict__ hWpl, float* __restrict__ agg,
                                                   int apply_relu) {
  __shared__ float Xs[64 * 64];
  __shared__ float Wcs[64 * 64];
  __shared__ float Wrs[64 * 64];
  int t = threadIdx.x;
#pragma unroll
  for (int j = 0; j < 4; j++) {
    ((float4*)Wcs)[t + j * 256] = ((const float4*)Wc)[t + j * 256];
    ((float4*)Wrs)[t + j * 256] = ((const float4*)Wr)[t + j * 256];
  }
  int n0 = blockIdx.x * 64;
#pragma unroll
  for (int i = 0; i < 4; i++) {
    int idx = t + i * 256;        // float4 index in 64x64 tile (1024 total)
    int n = idx >> 4;             // 16 float4 per row
    int kg = (idx & 15) << 2;
    float4 v = make_float4(0.f, 0.f, 0.f, 0.f);
    int gn = n0 + n;
    if (gn < NN) v = *(const float4*)(Xin + gn * 64 + kg);
    if (apply_relu) {
      v.x = fmaxf(v.x, 0.f); v.y = fmaxf(v.y, 0.f);
      v.z = fmaxf(v.z, 0.f); v.w = fmaxf(v.w, 0.f);
    }
    int sw = ((n >> 2) & 7) << 2;  // float4-preserving bank swizzle
    *(float4*)(Xs + n * 64 + (kg ^ sw)) = v;
  }
  __syncthreads();

  int hg = (t & 15) << 2;   // h0 (4 consecutive h)
  int ng = t >> 4;          // node group (16 groups x 4 nodes)
  int nb = ng << 2;
  int swz = (ng & 7) << 2;  // rows nb..nb+3 share row>>2 == ng

  float aC[4][4] = {};
  float aR[4][4] = {};
#pragma unroll 4
  for (int k = 0; k < 64; k++) {
    float4 wc = *(const float4*)(Wcs + k * 64 + hg);
    float4 wr = *(const float4*)(Wrs + k * 64 + hg);
    int kk = k ^ swz;
#pragma unroll
    for (int i = 0; i < 4; i++) {
      float xv = Xs[(nb + i) * 64 + kk];
      aC[i][0] += xv * wc.x; aC[i][1] += xv * wc.y; aC[i][2] += xv * wc.z; aC[i][3] += xv * wc.w;
      aR[i][0] += xv * wr.x; aR[i][1] += xv * wr.y; aR[i][2] += xv * wr.z; aR[i][3] += xv * wr.w;
    }
  }

  float4 cbv = *(const float4*)(cb + hg);
  float4 rbv = *(const float4*)(rb + hg);
  unsigned short* pl = hWpl + (hg < 32 ? 0 : (size_t)NPAD * 32);
  int ho = hg & 31;
#pragma unroll
  for (int i = 0; i < 4; i++) {
    int n = n0 + nb + i;
    if (n < NN) {
      float dv = dinv[n];
      float4 hv;
      hv.x = dv * aC[i][0]; hv.y = dv * aC[i][1]; hv.z = dv * aC[i][2]; hv.w = dv * aC[i][3];
      ushort4 hb;
      hb.x = f2bf(hv.x); hb.y = f2bf(hv.y); hb.z = f2bf(hv.z); hb.w = f2bf(hv.w);
      *(ushort4*)(pl + n * 32 + ho) = hb;
      float4 av;
      av.x = aR[i][0] + rbv.x + cbv.x + dv * hv.x;
      av.y = aR[i][1] + rbv.y + cbv.y + dv * hv.y;
      av.z = aR[i][2] + rbv.z + cbv.z + dv * hv.z;
      av.w = aR[i][3] + rbv.w + cbv.w + dv * hv.w;
      *(float4*)(agg + n * 64 + hg) = av;
    }
  }
}

// ---------------- plane gather: agg[n, hoff:hoff+32] += dinv[n] * sum_e plane[cols[e]] ----------------
// One wave per dst node; lane = (pair p, h in [0,32)). Each load instr serves TWO edges
// (2 x 64 B half-rows) -> 16 edges in flight per 8-load batch. Plane = 3.2 MB, fits
// per-XCD L2; cols/agg use non-temporal hints so streams don't evict the plane.
// Pass hoff=32 on the last layer fuses decode: Xo[n] = relu(X_final[n]) . decW.

__global__ __launch_bounds__(256) void k_gather_h(const int* __restrict__ rowptr, const int* __restrict__ cols,
                                                  const float* __restrict__ dinv,
                                                  const unsigned short* __restrict__ plane,
                                                  float* __restrict__ agg, int hoff,
                                                  const float* __restrict__ decW, float* __restrict__ Xo,
                                                  int last) {
  int lane = threadIdx.x & 63;
  int h = lane & 31;
  int p = lane >> 5;
  int n = __builtin_amdgcn_readfirstlane(blockIdx.x * 4 + (threadIdx.x >> 6));
  int st = rowptr[n];
  int en = rowptr[n + 1];
  int deg = en - st;
  float acc = 0.f;
  for (int base = 0; base < deg; base += 64) {
    int cnt = deg - base;
    if (cnt > 64) cnt = 64;
    int li = lane < cnt ? lane : cnt - 1;
    int colv = __builtin_nontemporal_load(&cols[st + base + li]);  // coalesced chunk of indices
    for (int j = 0; j < cnt; j += 16) {
      int i0 = j + 0 + p, i1 = j + 2 + p, i2 = j + 4 + p, i3 = j + 6 + p;
      int i4 = j + 8 + p, i5 = j + 10 + p, i6 = j + 12 + p, i7 = j + 14 + p;
      int s0 = __shfl(colv, i0 < cnt ? i0 : 0, 64);
      int s1 = __shfl(colv, i1 < cnt ? i1 : 0, 64);
      int s2 = __shfl(colv, i2 < cnt ? i2 : 0, 64);
      int s3 = __shfl(colv, i3 < cnt ? i3 : 0, 64);
      int s4 = __shfl(colv, i4 < cnt ? i4 : 0, 64);
      int s5 = __shfl(colv, i5 < cnt ? i5 : 0, 64);
      int s6 = __shfl(colv, i6 < cnt ? i6 : 0, 64);
      int s7 = __shfl(colv, i7 < cnt ? i7 : 0, 64);
      float v0 = bf2f(plane[s0 * 32 + h]);
      float v1 = bf2f(plane[s1 * 32 + h]);
      float v2 = bf2f(plane[s2 * 32 + h]);
      float v3 = bf2f(plane[s3 * 32 + h]);
      float v4 = bf2f(plane[s4 * 32 + h]);
      float v5 = bf2f(plane[s5 * 32 + h]);
      float v6 = bf2f(plane[s6 * 32 + h]);
      float v7 = bf2f(plane[s7 * 32 + h]);
      acc += (i0 < cnt) ? v0 : 0.f;
      acc += (i1 < cnt) ? v1 : 0.f;
      acc += (i2 < cnt) ? v2 : 0.f;
      acc += (i3 < cnt) ? v3 : 0.f;
      acc += (i4 < cnt) ? v4 : 0.f;
      acc += (i5 < cnt) ? v5 : 0.f;
      acc += (i6 < cnt) ? v6 : 0.f;
      acc += (i7 < cnt) ? v7 : 0.f;
    }
  }
  acc += __shfl_down(acc, 32, 64);  // combine the two edge-halves (same h)
  if (lane < 32) {
    float r = __builtin_nontemporal_load(&agg[n * 64 + hoff + lane]) + dinv[n] * acc;
    __builtin_nontemporal_store(r, &agg[n * 64 + hoff + lane]);
    if (last) {
      float alo = agg[n * 64 + lane];  // lo half updated by the hoff=0 pass
      float v = fmaxf(alo, 0.f) * decW[lane] + fmaxf(r, 0.f) * decW[32 + lane];
#pragma unroll
      for (int off = 16; off > 0; off >>= 1) v += __shfl_down(v, off, 64);
      if (lane == 0) Xo[n] = v;
    }
  }
}

// ---------------- graph pooling: out[g] = sum Xo[gptr[g]:gptr[g+1]] + cnt*decb ----------------

__global__ __launch_bounds__(256) void k_pool(const float* __restrict__ Xo, const int* __restrict__ gptr,
                                              const float* __restrict__ decb, float* __restrict__ out) {
  __shared__ float part[4];
  int g = blockIdx.x;
  int t = threadIdx.x;
  int st = gptr[g], en = gptr[g + 1];
  float v = 0.f;
  for (int i = st + t; i < en; i += 256) v += Xo[i];
#pragma unroll
  for (int off = 32; off > 0; off >>= 1) v += __shfl_down(v, off, 64);
  if ((t & 63) == 0) part[t >> 6] = v;
  __syncthreads();
  if (t == 0) out[g] = part[0] + part[1] + part[2] + part[3] + (float)(en - st) * decb[0];
}

// ---------------- launch ----------------

extern "C" void kernel_launch(void* const* d_in, const int* in_sizes, int n_in,
                              void* d_out, int out_size, void* d_ws, size_t ws_size,
                              hipStream_t stream) {
  (void)in_sizes; (void)n_in; (void)out_size; (void)ws_size;
  const float* x     = (const float*)d_in[0];
  const float* pos   = (const float*)d_in[1];
  const int*   ei    = (const int*)d_in[2];
  const int*   batch = (const int*)d_in[3];
  const float* encW  = (const float*)d_in[4];
  const float* encb  = (const float*)d_in[5];
  const float* convW = (const float*)d_in[6];
  const float* convb = (const float*)d_in[7];
  const float* resW  = (const float*)d_in[8];
  const float* resb  = (const float*)d_in[9];
  const float* decW  = (const float*)d_in[10];
  const float* decb  = (const float*)d_in[11];
  float* out = (float*)d_out;

  const int* src = ei;       // edge_index[0]
  const int* dst = ei + NE;  // edge_index[1]

  // workspace layout (4-byte elems)
  float*          ws     = (float*)d_ws;
  float*          dinv   = ws;                         // [NPAD]
  int*            rowptr = (int*)(ws + NPAD);          // [NPAD+64]
  int*            bcnt   = (int*)(ws + 2 * NPAD + 64); // [1024]
  int*            bptr   = bcnt + 1024;                // [NBKT+1]
  int*            bcur   = bptr + 1024;                // [NBKT]
  int*            gptr   = bcur + 1024;                // [NG+1]
  float*          Xo     = (float*)(gptr + 512);       // [NPAD]
  int*            colp   = (int*)(Xo + NPAD);          // [NE] packed (src<<6)|dstLow
  int*            cols   = colp + NE;                  // [NE] CSR-sorted src
  unsigned short* hWpl   = (unsigned short*)(cols + NE);  // [NPAD*64] bf16, 2 column-planes
  float*          bufA   = (float*)(hWpl + (size_t)NPAD * 64);  // [NN*NH]
  float*          bufB   = bufA + NN * NH;

  hipMemsetAsync(bcnt, 0, 1024 * sizeof(int), stream);

  k_bhist<<<(NE + 8191) / 8192, 256, 0, stream>>>(dst, bcnt);
  k_bscan<<<1, 256, 0, stream>>>(bcnt, bptr, bcur);
  k_bin<<<(NE + 8191) / 8192, 256, 0, stream>>>(src, dst, bcur, colp);
  k_csr<<<NBKT, 256, 0, stream>>>(bptr, colp, cols, dinv, rowptr);
  k_gptr<<<(NN + 255) / 256, 256, 0, stream>>>(batch, gptr);

  k_encoder<<<(NN + 3) / 4, 256, 0, stream>>>(x, pos, encW, encb, bufA);

  unsigned short* hWlo = hWpl;
  unsigned short* hWhi = hWpl + (size_t)NPAD * 32;

  float* Xc = bufA;
  float* aggb = bufB;
  for (int l = 0; l < 5; l++) {
    int last = (l == 4) ? 1 : 0;
    k_gemm_dual<<<NBKT, 256, 0, stream>>>(Xc, convW, resW, convb, resb, dinv, hWpl, aggb, l > 0 ? 1 : 0);
    k_gather_h<<<NN / 4, 256, 0, stream>>>(rowptr, cols, dinv, hWlo, aggb, 0, decW, Xo, 0);
    k_gather_h<<<NN / 4, 256, 0, stream>>>(rowptr, cols, dinv, hWhi, aggb, 32, decW, Xo, last);
    float* tmp = Xc; Xc = aggb; aggb = tmp;
  }
  k_pool<<<NG, 256, 0, stream>>>(Xo, gptr, decb, out);
}

// Round 9
// 356.748 us; speedup vs baseline: 1.2416x; 1.2416x over previous
//
#include <hip/hip_runtime.h>

#define NN 50000
#define NE 800000
#define NH 64
#define NG 500
#define NPAD 50176   // 196*256
#define NBKT 782     // ceil(NN/64) 64-node buckets

// fp32 -> bf16 round-to-nearest-even
__device__ __forceinline__ unsigned short f2bf(float f) {
  unsigned x = __float_as_uint(f);
  unsigned r = ((x >> 16) & 1u) + 0x7fffu;
  return (unsigned short)((x + r) >> 16);
}
__device__ __forceinline__ float bf2f(unsigned short u) {
  return __uint_as_float(((unsigned)u) << 16);
}

// ---------------- per-bucket histogram (LDS-aggregated) ----------------

__global__ __launch_bounds__(256) void k_bhist(const int* __restrict__ dst, int* __restrict__ bcnt) {
  __shared__ int hist[NBKT];
  int t = threadIdx.x;
  for (int b = t; b < NBKT; b += 256) hist[b] = 0;
  __syncthreads();
  int e0 = blockIdx.x * 8192;
#pragma unroll
  for (int i = 0; i < 32; i++) {
    int e = e0 + i * 256 + t;
    if (e < NE) atomicAdd(&hist[dst[e] >> 6], 1);
  }
  __syncthreads();
  for (int b = t; b < NBKT; b += 256) {
    int c = hist[b];
    if (c) atomicAdd(&bcnt[b], c);
  }
}

// ---------------- bucket exclusive scan (single block, 4 elems/thread) ----------------

__global__ __launch_bounds__(256) void k_bscan(const int* __restrict__ bcnt, int* __restrict__ bptr,
                                               int* __restrict__ bcur) {
  __shared__ int s[256];
  int t = threadIdx.x;
  int base = t * 4;
  int v0 = (base + 0 < NBKT) ? bcnt[base + 0] : 0;
  int v1 = (base + 1 < NBKT) ? bcnt[base + 1] : 0;
  int v2 = (base + 2 < NBKT) ? bcnt[base + 2] : 0;
  int v3 = (base + 3 < NBKT) ? bcnt[base + 3] : 0;
  int lsum = v0 + v1 + v2 + v3;
  s[t] = lsum;
  __syncthreads();
#pragma unroll
  for (int off = 1; off < 256; off <<= 1) {
    int x = (t >= off) ? s[t - off] : 0;
    __syncthreads();
    s[t] += x;
    __syncthreads();
  }
  int pre = s[t] - lsum;
  int p0 = pre, p1 = pre + v0, p2 = p1 + v1, p3 = p2 + v2;
  if (base + 0 < NBKT) { bptr[base + 0] = p0; bcur[base + 0] = p0; }
  if (base + 1 < NBKT) { bptr[base + 1] = p1; bcur[base + 1] = p1; }
  if (base + 2 < NBKT) { bptr[base + 2] = p2; bcur[base + 2] = p2; }
  if (base + 3 < NBKT) { bptr[base + 3] = p3; bcur[base + 3] = p3; }
  if (t == 255) bptr[NBKT] = s[255];  // == NE
}

// ---------------- binning: colp[] = packed edges grouped by 64-node dst bucket ----------------

__global__ __launch_bounds__(256) void k_bin(const int* __restrict__ src, const int* __restrict__ dst,
                                             int* __restrict__ bcur, int* __restrict__ colp) {
  __shared__ int hist[NBKT];
  __shared__ int gbase[NBKT];
  int t = threadIdx.x;
  for (int b = t; b < NBKT; b += 256) hist[b] = 0;
  __syncthreads();
  int e0 = blockIdx.x * 8192;
#pragma unroll
  for (int i = 0; i < 32; i++) {
    int e = e0 + i * 256 + t;
    if (e < NE) atomicAdd(&hist[dst[e] >> 6], 1);
  }
  __syncthreads();
  for (int b = t; b < NBKT; b += 256) {
    int c = hist[b];
    gbase[b] = c ? atomicAdd(&bcur[b], c) : 0;
    hist[b] = 0;  // reuse as rank counter
  }
  __syncthreads();
#pragma unroll
  for (int i = 0; i < 32; i++) {
    int e = e0 + i * 256 + t;
    if (e < NE) {
      int s = src[e], d = dst[e];
      int b = d >> 6;
      int r = atomicAdd(&hist[b], 1);
      colp[gbase[b] + r] = (s << 6) | (d & 63);
    }
  }
}

// ---------------- bucket-local sort to exact CSR + deg/dinv/rowptr (+ gptr folded in) ----------------

__global__ __launch_bounds__(256) void k_csr(const int* __restrict__ bptr, const int* __restrict__ colp,
                                             int* __restrict__ cols, float* __restrict__ dinv,
                                             int* __restrict__ rowptr,
                                             const int* __restrict__ batch, int* __restrict__ gptr) {
  __shared__ int hist[64];
  __shared__ int excl[65];
  int t = threadIdx.x;
  int b = blockIdx.x;

  // folded gptr: graph segment pointers from sorted batch (independent work)
  int tid = b * 256 + t;
  if (tid < NN) {
    int bi = batch[tid];
    int bp = (tid > 0) ? batch[tid - 1] : -1;
    for (int g = bp + 1; g <= bi; g++) gptr[g] = tid;
    if (tid == NN - 1) {
      for (int g = bi + 1; g <= NG; g++) gptr[g] = NN;
    }
  }

  int st = bptr[b], en = bptr[b + 1];
  if (t < 64) hist[t] = 0;
  __syncthreads();
  for (int e = st + t; e < en; e += 256) atomicAdd(&hist[colp[e] & 63], 1);
  __syncthreads();
  if (t == 0) {
    int run = 0;
#pragma unroll
    for (int i = 0; i < 64; i++) { excl[i] = run; run += hist[i]; }
    excl[64] = run;
  }
  __syncthreads();
  if (t < 64) {
    int n = b * 64 + t;
    rowptr[n] = st + excl[t];
    if (n < NN) dinv[n] = rsqrtf((float)(hist[t] + 1));  // +1 self-loop
    hist[t] = 0;  // reuse as cursor
  }
  if (b == NBKT - 1 && t == 64) rowptr[NBKT * 64] = en;  // == NE
  __syncthreads();
  for (int e = st + t; e < en; e += 256) {
    int w = colp[e];
    int d = w & 63;
    int r = atomicAdd(&hist[d], 1);
    cols[st + excl[d] + r] = w >> 6;
  }
}

// ---------------- encoder: X0 = [x|pos] @ enc_W + enc_b ----------------

__global__ __launch_bounds__(256) void k_encoder(const float* __restrict__ x, const float* __restrict__ pos,
                                                 const float* __restrict__ W, const float* __restrict__ b,
                                                 float* __restrict__ X0) {
  __shared__ float Ws[16 * 64];
  __shared__ float bs[64];
  int t = threadIdx.x;
  for (int i = t; i < 1024; i += 256) Ws[i] = W[i];
  if (t < 64) bs[t] = b[t];
  __syncthreads();
  int n = blockIdx.x * 4 + (t >> 6);
  int h = t & 63;
  if (n >= NN) return;
  float acc = bs[h];
#pragma unroll
  for (int f = 0; f < 14; f++) acc += x[n * 14 + f] * Ws[f * 64 + h];
  acc += pos[n * 2 + 0] * Ws[14 * 64 + h];
  acc += pos[n * 2 + 1] * Ws[15 * 64 + h];
  X0[n * 64 + h] = acc;
}

// ---------------- fused dual GEMM + epilogue (64-node tile, 48 KB LDS -> 3 blocks/CU) ----------------
// hWbf = bf16( dinv[n] * (relu?(X) @ conv_W) )   (gather sums these)
// agg  = relu?(X) @ res_W + res_b + conv_b + dinv[n] * hWs[n]   (self-loop in fp32)

__global__ __launch_bounds__(256) void k_gemm_dual(const float* __restrict__ Xin,
                                                   const float* __restrict__ Wc, const float* __restrict__ Wr,
                                                   const float* __restrict__ cb, const float* __restrict__ rb,
                                                   const float* __restrict__ dinv,
                                                   unsigned short* __restrict__ hWbf, float* __restrict__ agg,
                                                   int apply_relu) {
  __shared__ float Xs[64 * 64];
  __shared__ float Wcs[64 * 64];
  __shared__ float Wrs[64 * 64];
  int t = threadIdx.x;
#pragma unroll
  for (int j = 0; j < 4; j++) {
    ((float4*)Wcs)[t + j * 256] = ((const float4*)Wc)[t + j * 256];
    ((float4*)Wrs)[t + j * 256] = ((const float4*)Wr)[t + j * 256];
  }
  int n0 = blockIdx.x * 64;
#pragma unroll
  for (int i = 0; i < 4; i++) {
    int idx = t + i * 256;        // float4 index in 64x64 tile (1024 total)
    int n = idx >> 4;             // 16 float4 per row
    int kg = (idx & 15) << 2;
    float4 v = make_float4(0.f, 0.f, 0.f, 0.f);
    int gn = n0 + n;
    if (gn < NN) v = *(const float4*)(Xin + gn * 64 + kg);
    if (apply_relu) {
      v.x = fmaxf(v.x, 0.f); v.y = fmaxf(v.y, 0.f);
      v.z = fmaxf(v.z, 0.f); v.w = fmaxf(v.w, 0.f);
    }
    int sw = ((n >> 2) & 7) << 2;  // float4-preserving bank swizzle
    *(float4*)(Xs + n * 64 + (kg ^ sw)) = v;
  }
  __syncthreads();

  int hg = (t & 15) << 2;   // h0 (4 consecutive h)
  int ng = t >> 4;          // node group (16 groups x 4 nodes)
  int nb = ng << 2;
  int swz = (ng & 7) << 2;  // rows nb..nb+3 share row>>2 == ng

  float aC[4][4] = {};
  float aR[4][4] = {};
#pragma unroll 4
  for (int k = 0; k < 64; k++) {
    float4 wc = *(const float4*)(Wcs + k * 64 + hg);
    float4 wr = *(const float4*)(Wrs + k * 64 + hg);
    int kk = k ^ swz;
#pragma unroll
    for (int i = 0; i < 4; i++) {
      float xv = Xs[(nb + i) * 64 + kk];
      aC[i][0] += xv * wc.x; aC[i][1] += xv * wc.y; aC[i][2] += xv * wc.z; aC[i][3] += xv * wc.w;
      aR[i][0] += xv * wr.x; aR[i][1] += xv * wr.y; aR[i][2] += xv * wr.z; aR[i][3] += xv * wr.w;
    }
  }

  float4 cbv = *(const float4*)(cb + hg);
  float4 rbv = *(const float4*)(rb + hg);
#pragma unroll
  for (int i = 0; i < 4; i++) {
    int n = n0 + nb + i;
    if (n < NN) {
      float dv = dinv[n];
      float4 hv;
      hv.x = dv * aC[i][0]; hv.y = dv * aC[i][1]; hv.z = dv * aC[i][2]; hv.w = dv * aC[i][3];
      ushort4 hb;
      hb.x = f2bf(hv.x); hb.y = f2bf(hv.y); hb.z = f2bf(hv.z); hb.w = f2bf(hv.w);
      *(ushort4*)(hWbf + n * 64 + hg) = hb;
      float4 av;
      av.x = aR[i][0] + rbv.x + cbv.x + dv * hv.x;
      av.y = aR[i][1] + rbv.y + cbv.y + dv * hv.y;
      av.z = aR[i][2] + rbv.z + cbv.z + dv * hv.z;
      av.w = aR[i][3] + rbv.w + cbv.w + dv * hv.w;
      *(float4*)(agg + n * 64 + hg) = av;
    }
  }
}

// ---------------- CSR gather: agg[n] += dinv[n] * sum_e bf2f(hWbf[cols[e]]) ----------------
// One 64-lane wave per dst node; full 128 B row per load (one cache line). ILP-16:
// sixteen independent row-loads in flight — avg-degree rows finish in ONE batch.
// Last layer fuses decode GEMV: Xo[n] = relu(X_final[n]) . decW.

__global__ __launch_bounds__(256) void k_gather(const int* __restrict__ rowptr, const int* __restrict__ cols,
                                                const float* __restrict__ dinv,
                                                const unsigned short* __restrict__ hWbf,
                                                float* __restrict__ agg,
                                                const float* __restrict__ decW, float* __restrict__ Xo,
                                                int last) {
  int lane = threadIdx.x & 63;
  int n = __builtin_amdgcn_readfirstlane(blockIdx.x * 4 + (threadIdx.x >> 6));
  int st = rowptr[n];
  int en = rowptr[n + 1];
  int deg = en - st;
  float acc = 0.f;
  for (int base = 0; base < deg; base += 64) {
    int cnt = deg - base;
    if (cnt > 64) cnt = 64;
    int li = lane < cnt ? lane : cnt - 1;
    int colv = cols[st + base + li];  // one coalesced row-load of up to 64 indices
    for (int j = 0; j < cnt; j += 16) {
      int i0 = j + 0, i1 = j + 1, i2 = j + 2, i3 = j + 3;
      int i4 = j + 4, i5 = j + 5, i6 = j + 6, i7 = j + 7;
      int i8 = j + 8, i9 = j + 9, iA = j + 10, iB = j + 11;
      int iC = j + 12, iD = j + 13, iE = j + 14, iF = j + 15;
      int s0 = __shfl(colv, i0, 64);
      int s1 = __shfl(colv, i1 < cnt ? i1 : j, 64);
      int s2 = __shfl(colv, i2 < cnt ? i2 : j, 64);
      int s3 = __shfl(colv, i3 < cnt ? i3 : j, 64);
      int s4 = __shfl(colv, i4 < cnt ? i4 : j, 64);
      int s5 = __shfl(colv, i5 < cnt ? i5 : j, 64);
      int s6 = __shfl(colv, i6 < cnt ? i6 : j, 64);
      int s7 = __shfl(colv, i7 < cnt ? i7 : j, 64);
      int s8 = __shfl(colv, i8 < cnt ? i8 : j, 64);
      int s9 = __shfl(colv, i9 < cnt ? i9 : j, 64);
      int sA = __shfl(colv, iA < cnt ? iA : j, 64);
      int sB = __shfl(colv, iB < cnt ? iB : j, 64);
      int sC = __shfl(colv, iC < cnt ? iC : j, 64);
      int sD = __shfl(colv, iD < cnt ? iD : j, 64);
      int sE = __shfl(colv, iE < cnt ? iE : j, 64);
      int sF = __shfl(colv, iF < cnt ? iF : j, 64);
      float v0 = bf2f(hWbf[s0 * 64 + lane]);
      float v1 = bf2f(hWbf[s1 * 64 + lane]);
      float v2 = bf2f(hWbf[s2 * 64 + lane]);
      float v3 = bf2f(hWbf[s3 * 64 + lane]);
      float v4 = bf2f(hWbf[s4 * 64 + lane]);
      float v5 = bf2f(hWbf[s5 * 64 + lane]);
      float v6 = bf2f(hWbf[s6 * 64 + lane]);
      float v7 = bf2f(hWbf[s7 * 64 + lane]);
      float v8 = bf2f(hWbf[s8 * 64 + lane]);
      float v9 = bf2f(hWbf[s9 * 64 + lane]);
      float vA = bf2f(hWbf[sA * 64 + lane]);
      float vB = bf2f(hWbf[sB * 64 + lane]);
      float vC = bf2f(hWbf[sC * 64 + lane]);
      float vD = bf2f(hWbf[sD * 64 + lane]);
      float vE = bf2f(hWbf[sE * 64 + lane]);
      float vF = bf2f(hWbf[sF * 64 + lane]);
      acc += v0;
      acc += (i1 < cnt) ? v1 : 0.f;
      acc += (i2 < cnt) ? v2 : 0.f;
      acc += (i3 < cnt) ? v3 : 0.f;
      acc += (i4 < cnt) ? v4 : 0.f;
      acc += (i5 < cnt) ? v5 : 0.f;
      acc += (i6 < cnt) ? v6 : 0.f;
      acc += (i7 < cnt) ? v7 : 0.f;
      acc += (i8 < cnt) ? v8 : 0.f;
      acc += (i9 < cnt) ? v9 : 0.f;
      acc += (iA < cnt) ? vA : 0.f;
      acc += (iB < cnt) ? vB : 0.f;
      acc += (iC < cnt) ? vC : 0.f;
      acc += (iD < cnt) ? vD : 0.f;
      acc += (iE < cnt) ? vE : 0.f;
      acc += (iF < cnt) ? vF : 0.f;
    }
  }
  float r = agg[n * 64 + lane] + dinv[n] * acc;
  agg[n * 64 + lane] = r;
  if (last) {
    float v = fmaxf(r, 0.f) * decW[lane];
#pragma unroll
    for (int off = 32; off > 0; off >>= 1) v += __shfl_down(v, off, 64);
    if (lane == 0) Xo[n] = v;
  }
}

// ---------------- graph pooling: out[g] = sum Xo[gptr[g]:gptr[g+1]] + cnt*decb ----------------

__global__ __launch_bounds__(256) void k_pool(const float* __restrict__ Xo, const int* __restrict__ gptr,
                                              const float* __restrict__ decb, float* __restrict__ out) {
  __shared__ float part[4];
  int g = blockIdx.x;
  int t = threadIdx.x;
  int st = gptr[g], en = gptr[g + 1];
  float v = 0.f;
  for (int i = st + t; i < en; i += 256) v += Xo[i];
#pragma unroll
  for (int off = 32; off > 0; off >>= 1) v += __shfl_down(v, off, 64);
  if ((t & 63) == 0) part[t >> 6] = v;
  __syncthreads();
  if (t == 0) out[g] = part[0] + part[1] + part[2] + part[3] + (float)(en - st) * decb[0];
}

// ---------------- launch ----------------

extern "C" void kernel_launch(void* const* d_in, const int* in_sizes, int n_in,
                              void* d_out, int out_size, void* d_ws, size_t ws_size,
                              hipStream_t stream) {
  (void)in_sizes; (void)n_in; (void)out_size; (void)ws_size;
  const float* x     = (const float*)d_in[0];
  const float* pos   = (const float*)d_in[1];
  const int*   ei    = (const int*)d_in[2];
  const int*   batch = (const int*)d_in[3];
  const float* encW  = (const float*)d_in[4];
  const float* encb  = (const float*)d_in[5];
  const float* convW = (const float*)d_in[6];
  const float* convb = (const float*)d_in[7];
  const float* resW  = (const float*)d_in[8];
  const float* resb  = (const float*)d_in[9];
  const float* decW  = (const float*)d_in[10];
  const float* decb  = (const float*)d_in[11];
  float* out = (float*)d_out;

  const int* src = ei;       // edge_index[0]
  const int* dst = ei + NE;  // edge_index[1]

  // workspace layout (4-byte elems)
  float*          ws     = (float*)d_ws;
  float*          dinv   = ws;                         // [NPAD]
  int*            rowptr = (int*)(ws + NPAD);          // [NPAD+64]
  int*            bcnt   = (int*)(ws + 2 * NPAD + 64); // [1024]
  int*            bptr   = bcnt + 1024;                // [NBKT+1]
  int*            bcur   = bptr + 1024;                // [NBKT]
  int*            gptr   = bcur + 1024;                // [NG+1]
  float*          Xo     = (float*)(gptr + 512);       // [NPAD]
  int*            colp   = (int*)(Xo + NPAD);          // [NE] packed (src<<6)|dstLow
  int*            cols   = colp + NE;                  // [NE] CSR-sorted src
  unsigned short* hWbf   = (unsigned short*)(cols + NE);  // [NPAD*64] bf16
  float*          bufA   = (float*)(hWbf + (size_t)NPAD * 64);  // [NN*NH]
  float*          bufB   = bufA + NN * NH;

  hipMemsetAsync(bcnt, 0, 1024 * sizeof(int), stream);

  k_bhist<<<(NE + 8191) / 8192, 256, 0, stream>>>(dst, bcnt);
  k_bscan<<<1, 256, 0, stream>>>(bcnt, bptr, bcur);
  k_bin<<<(NE + 8191) / 8192, 256, 0, stream>>>(src, dst, bcur, colp);
  k_csr<<<NBKT, 256, 0, stream>>>(bptr, colp, cols, dinv, rowptr, batch, gptr);

  k_encoder<<<(NN + 3) / 4, 256, 0, stream>>>(x, pos, encW, encb, bufA);

  float* Xc = bufA;
  float* aggb = bufB;
  for (int l = 0; l < 5; l++) {
    k_gemm_dual<<<NBKT, 256, 0, stream>>>(Xc, convW, resW, convb, resb, dinv, hWbf, aggb, l > 0 ? 1 : 0);
    k_gather<<<NN / 4, 256, 0, stream>>>(rowptr, cols, dinv, hWbf, aggb, decW, Xo, l == 4 ? 1 : 0);
    float* tmp = Xc; Xc = aggb; aggb = tmp;
  }
  k_pool<<<NG, 256, 0, stream>>>(Xo, gptr, decb, out);
}

// Round 10
// 339.838 us; speedup vs baseline: 1.3033x; 1.0498x over previous
//
#include <hip/hip_runtime.h>

#define NN 50000
#define NE 800000
#define NH 64
#define NG 500
#define NPAD 50176   // 196*256
#define NBKT 782     // ceil(NN/64) 64-node buckets
#define CAP 1536     // padded bucket capacity (max bucket deg ~1170 = 1024+4.5 sigma)

// fp32 -> bf16 round-to-nearest-even
__device__ __forceinline__ unsigned short f2bf(float f) {
  unsigned x = __float_as_uint(f);
  unsigned r = ((x >> 16) & 1u) + 0x7fffu;
  return (unsigned short)((x + r) >> 16);
}
__device__ __forceinline__ float bf2f(unsigned short u) {
  return __uint_as_float(((unsigned)u) << 16);
}

// ---------------- binning into padded buckets: colp[b*CAP + r] ----------------
// word = (src<<6) | (dst&63). LDS histogram -> one bulk reserve per (block,bucket)
// via atomicAdd(bcur[b]) -> rank-addressed line-dense writes. No scan needed.

__global__ __launch_bounds__(256) void k_bin(const int* __restrict__ src, const int* __restrict__ dst,
                                             int* __restrict__ bcur, int* __restrict__ colp) {
  __shared__ int hist[NBKT];
  __shared__ int gbase[NBKT];
  int t = threadIdx.x;
  for (int b = t; b < NBKT; b += 256) hist[b] = 0;
  __syncthreads();
  int e0 = blockIdx.x * 8192;
#pragma unroll
  for (int i = 0; i < 32; i++) {
    int e = e0 + i * 256 + t;
    if (e < NE) atomicAdd(&hist[dst[e] >> 6], 1);
  }
  __syncthreads();
  for (int b = t; b < NBKT; b += 256) {
    int c = hist[b];
    gbase[b] = c ? atomicAdd(&bcur[b], c) : 0;
    hist[b] = 0;  // reuse as rank counter
  }
  __syncthreads();
#pragma unroll
  for (int i = 0; i < 32; i++) {
    int e = e0 + i * 256 + t;
    if (e < NE) {
      int s = src[e], d = dst[e];
      int b = d >> 6;
      int r = atomicAdd(&hist[b], 1);
      colp[b * CAP + gbase[b] + r] = (s << 6) | (d & 63);
    }
  }
}

// ---------------- bucket-local sort to padded CSR + dinv/rowst/rowen (+ gptr folded) ----------------

__global__ __launch_bounds__(256) void k_csr(const int* __restrict__ bcur, const int* __restrict__ colp,
                                             int* __restrict__ cols, float* __restrict__ dinv,
                                             int* __restrict__ rowst, int* __restrict__ rowen,
                                             const int* __restrict__ batch, int* __restrict__ gptr) {
  __shared__ int hist[64];
  __shared__ int excl[65];
  int t = threadIdx.x;
  int b = blockIdx.x;

  // folded gptr: graph segment pointers from sorted batch (independent work)
  int tid = b * 256 + t;
  if (tid < NN) {
    int bi = batch[tid];
    int bp = (tid > 0) ? batch[tid - 1] : -1;
    for (int g = bp + 1; g <= bi; g++) gptr[g] = tid;
    if (tid == NN - 1) {
      for (int g = bi + 1; g <= NG; g++) gptr[g] = NN;
    }
  }

  int base = b * CAP;
  int cnt = bcur[b];
  if (t < 64) hist[t] = 0;
  __syncthreads();
  for (int e = t; e < cnt; e += 256) atomicAdd(&hist[colp[base + e] & 63], 1);
  __syncthreads();
  if (t == 0) {
    int run = 0;
#pragma unroll
    for (int i = 0; i < 64; i++) { excl[i] = run; run += hist[i]; }
    excl[64] = run;
  }
  __syncthreads();
  if (t < 64) {
    int n = b * 64 + t;
    rowst[n] = base + excl[t];
    rowen[n] = base + excl[t + 1];
    if (n < NN) dinv[n] = rsqrtf((float)(hist[t] + 1));  // +1 self-loop
    hist[t] = 0;  // reuse as cursor
  }
  __syncthreads();
  for (int e = t; e < cnt; e += 256) {
    int w = colp[base + e];
    int d = w & 63;
    int r = atomicAdd(&hist[d], 1);
    cols[base + excl[d] + r] = w >> 6;
  }
}

// ---------------- encoder: X0 = [x|pos] @ enc_W + enc_b ----------------

__global__ __launch_bounds__(256) void k_encoder(const float* __restrict__ x, const float* __restrict__ pos,
                                                 const float* __restrict__ W, const float* __restrict__ b,
                                                 float* __restrict__ X0) {
  __shared__ float Ws[16 * 64];
  __shared__ float bs[64];
  int t = threadIdx.x;
  for (int i = t; i < 1024; i += 256) Ws[i] = W[i];
  if (t < 64) bs[t] = b[t];
  __syncthreads();
  int n = blockIdx.x * 4 + (t >> 6);
  int h = t & 63;
  if (n >= NN) return;
  float acc = bs[h];
#pragma unroll
  for (int f = 0; f < 14; f++) acc += x[n * 14 + f] * Ws[f * 64 + h];
  acc += pos[n * 2 + 0] * Ws[14 * 64 + h];
  acc += pos[n * 2 + 1] * Ws[15 * 64 + h];
  X0[n * 64 + h] = acc;
}

// ---------------- fused dual GEMM + epilogue (64-node tile, 48 KB LDS -> 3 blocks/CU) ----------------
// mode 0: X = Xin (encoder output, no relu, no gsum)
// mode 1: X = relu(Xin + dinv[n] * bf2f(gsum[n]))   (reconstructs the layer state)
// hWbf = bf16( dinv[n] * (X @ conv_W) )             (gather sums these)
// agg  = X @ res_W + res_b + conv_b + dinv[n] * hWs[n]   (self-loop folded, fp32)

__global__ __launch_bounds__(256) void k_gemm_dual(const float* __restrict__ Xin,
                                                   const unsigned short* __restrict__ gsum,
                                                   const float* __restrict__ Wc, const float* __restrict__ Wr,
                                                   const float* __restrict__ cb, const float* __restrict__ rb,
                                                   const float* __restrict__ dinv,
                                                   unsigned short* __restrict__ hWbf, float* __restrict__ agg,
                                                   int mode) {
  __shared__ float Xs[64 * 64];
  __shared__ float Wcs[64 * 64];
  __shared__ float Wrs[64 * 64];
  int t = threadIdx.x;
#pragma unroll
  for (int j = 0; j < 4; j++) {
    ((float4*)Wcs)[t + j * 256] = ((const float4*)Wc)[t + j * 256];
    ((float4*)Wrs)[t + j * 256] = ((const float4*)Wr)[t + j * 256];
  }
  int n0 = blockIdx.x * 64;
#pragma unroll
  for (int i = 0; i < 4; i++) {
    int idx = t + i * 256;        // float4 index in 64x64 tile (1024 total)
    int n = idx >> 4;             // 16 float4 per row
    int kg = (idx & 15) << 2;
    float4 v = make_float4(0.f, 0.f, 0.f, 0.f);
    int gn = n0 + n;
    if (gn < NN) {
      v = *(const float4*)(Xin + gn * 64 + kg);
      if (mode) {
        ushort4 g = *(const ushort4*)(gsum + gn * 64 + kg);
        float dvn = dinv[gn];
        v.x = fmaxf(v.x + dvn * bf2f(g.x), 0.f);
        v.y = fmaxf(v.y + dvn * bf2f(g.y), 0.f);
        v.z = fmaxf(v.z + dvn * bf2f(g.z), 0.f);
        v.w = fmaxf(v.w + dvn * bf2f(g.w), 0.f);
      }
    }
    int sw = ((n >> 2) & 7) << 2;  // float4-preserving bank swizzle
    *(float4*)(Xs + n * 64 + (kg ^ sw)) = v;
  }
  __syncthreads();

  int hg = (t & 15) << 2;   // h0 (4 consecutive h)
  int ng = t >> 4;          // node group (16 groups x 4 nodes)
  int nb = ng << 2;
  int swz = (ng & 7) << 2;  // rows nb..nb+3 share row>>2 == ng

  float aC[4][4] = {};
  float aR[4][4] = {};
#pragma unroll 4
  for (int k = 0; k < 64; k++) {
    float4 wc = *(const float4*)(Wcs + k * 64 + hg);
    float4 wr = *(const float4*)(Wrs + k * 64 + hg);
    int kk = k ^ swz;
#pragma unroll
    for (int i = 0; i < 4; i++) {
      float xv = Xs[(nb + i) * 64 + kk];
      aC[i][0] += xv * wc.x; aC[i][1] += xv * wc.y; aC[i][2] += xv * wc.z; aC[i][3] += xv * wc.w;
      aR[i][0] += xv * wr.x; aR[i][1] += xv * wr.y; aR[i][2] += xv * wr.z; aR[i][3] += xv * wr.w;
    }
  }

  float4 cbv = *(const float4*)(cb + hg);
  float4 rbv = *(const float4*)(rb + hg);
#pragma unroll
  for (int i = 0; i < 4; i++) {
    int n = n0 + nb + i;
    if (n < NN) {
      float dv = dinv[n];
      float4 hv;
      hv.x = dv * aC[i][0]; hv.y = dv * aC[i][1]; hv.z = dv * aC[i][2]; hv.w = dv * aC[i][3];
      ushort4 hb;
      hb.x = f2bf(hv.x); hb.y = f2bf(hv.y); hb.z = f2bf(hv.z); hb.w = f2bf(hv.w);
      *(ushort4*)(hWbf + n * 64 + hg) = hb;
      float4 av;
      av.x = aR[i][0] + rbv.x + cbv.x + dv * hv.x;
      av.y = aR[i][1] + rbv.y + cbv.y + dv * hv.y;
      av.z = aR[i][2] + rbv.z + cbv.z + dv * hv.z;
      av.w = aR[i][3] + rbv.w + cbv.w + dv * hv.w;
      *(float4*)(agg + n * 64 + hg) = av;
    }
  }
}

// ---------------- CSR gather: gsum[n] = bf16( sum_e bf2f(hWbf[cols[e]]) ) ----------------
// One 64-lane wave per dst node; full 128 B row per load. ILP-16. No agg traffic —
// the next gemm reconstructs X = relu(agg + dinv*gsum) during staging.
// Last layer reads agg once and fuses decode: Xo[n] = relu(X_final[n]) . decW.

__global__ __launch_bounds__(256) void k_gather(const int* __restrict__ rowst, const int* __restrict__ rowen,
                                                const int* __restrict__ cols,
                                                const unsigned short* __restrict__ hWbf,
                                                unsigned short* __restrict__ gsum,
                                                const float* __restrict__ agg, const float* __restrict__ dinv,
                                                const float* __restrict__ decW, float* __restrict__ Xo,
                                                int last) {
  int lane = threadIdx.x & 63;
  int n = __builtin_amdgcn_readfirstlane(blockIdx.x * 4 + (threadIdx.x >> 6));
  int st = rowst[n];
  int en = rowen[n];
  int deg = en - st;
  float acc = 0.f;
  for (int base = 0; base < deg; base += 64) {
    int cnt = deg - base;
    if (cnt > 64) cnt = 64;
    int li = lane < cnt ? lane : cnt - 1;
    int colv = cols[st + base + li];  // one coalesced row-load of up to 64 indices
    for (int j = 0; j < cnt; j += 16) {
      int i0 = j + 0, i1 = j + 1, i2 = j + 2, i3 = j + 3;
      int i4 = j + 4, i5 = j + 5, i6 = j + 6, i7 = j + 7;
      int i8 = j + 8, i9 = j + 9, iA = j + 10, iB = j + 11;
      int iC = j + 12, iD = j + 13, iE = j + 14, iF = j + 15;
      int s0 = __shfl(colv, i0, 64);
      int s1 = __shfl(colv, i1 < cnt ? i1 : j, 64);
      int s2 = __shfl(colv, i2 < cnt ? i2 : j, 64);
      int s3 = __shfl(colv, i3 < cnt ? i3 : j, 64);
      int s4 = __shfl(colv, i4 < cnt ? i4 : j, 64);
      int s5 = __shfl(colv, i5 < cnt ? i5 : j, 64);
      int s6 = __shfl(colv, i6 < cnt ? i6 : j, 64);
      int s7 = __shfl(colv, i7 < cnt ? i7 : j, 64);
      int s8 = __shfl(colv, i8 < cnt ? i8 : j, 64);
      int s9 = __shfl(colv, i9 < cnt ? i9 : j, 64);
      int sA = __shfl(colv, iA < cnt ? iA : j, 64);
      int sB = __shfl(colv, iB < cnt ? iB : j, 64);
      int sC = __shfl(colv, iC < cnt ? iC : j, 64);
      int sD = __shfl(colv, iD < cnt ? iD : j, 64);
      int sE = __shfl(colv, iE < cnt ? iE : j, 64);
      int sF = __shfl(colv, iF < cnt ? iF : j, 64);
      float v0 = bf2f(hWbf[s0 * 64 + lane]);
      float v1 = bf2f(hWbf[s1 * 64 + lane]);
      float v2 = bf2f(hWbf[s2 * 64 + lane]);
      float v3 = bf2f(hWbf[s3 * 64 + lane]);
      float v4 = bf2f(hWbf[s4 * 64 + lane]);
      float v5 = bf2f(hWbf[s5 * 64 + lane]);
      float v6 = bf2f(hWbf[s6 * 64 + lane]);
      float v7 = bf2f(hWbf[s7 * 64 + lane]);
      float v8 = bf2f(hWbf[s8 * 64 + lane]);
      float v9 = bf2f(hWbf[s9 * 64 + lane]);
      float vA = bf2f(hWbf[sA * 64 + lane]);
      float vB = bf2f(hWbf[sB * 64 + lane]);
      float vC = bf2f(hWbf[sC * 64 + lane]);
      float vD = bf2f(hWbf[sD * 64 + lane]);
      float vE = bf2f(hWbf[sE * 64 + lane]);
      float vF = bf2f(hWbf[sF * 64 + lane]);
      acc += v0;
      acc += (i1 < cnt) ? v1 : 0.f;
      acc += (i2 < cnt) ? v2 : 0.f;
      acc += (i3 < cnt) ? v3 : 0.f;
      acc += (i4 < cnt) ? v4 : 0.f;
      acc += (i5 < cnt) ? v5 : 0.f;
      acc += (i6 < cnt) ? v6 : 0.f;
      acc += (i7 < cnt) ? v7 : 0.f;
      acc += (i8 < cnt) ? v8 : 0.f;
      acc += (i9 < cnt) ? v9 : 0.f;
      acc += (iA < cnt) ? vA : 0.f;
      acc += (iB < cnt) ? vB : 0.f;
      acc += (iC < cnt) ? vC : 0.f;
      acc += (iD < cnt) ? vD : 0.f;
      acc += (iE < cnt) ? vE : 0.f;
      acc += (iF < cnt) ? vF : 0.f;
    }
  }
  gsum[n * 64 + lane] = f2bf(acc);
  if (last) {
    float xf = agg[n * 64 + lane] + dinv[n] * acc;  // X_final pre-relu (fp32 acc)
    float v = fmaxf(xf, 0.f) * decW[lane];
#pragma unroll
    for (int off = 32; off > 0; off >>= 1) v += __shfl_down(v, off, 64);
    if (lane == 0) Xo[n] = v;
  }
}

// ---------------- graph pooling: out[g] = sum Xo[gptr[g]:gptr[g+1]] + cnt*decb ----------------

__global__ __launch_bounds__(256) void k_pool(const float* __restrict__ Xo, const int* __restrict__ gptr,
                                              const float* __restrict__ decb, float* __restrict__ out) {
  __shared__ float part[4];
  int g = blockIdx.x;
  int t = threadIdx.x;
  int st = gptr[g], en = gptr[g + 1];
  float v = 0.f;
  for (int i = st + t; i < en; i += 256) v += Xo[i];
#pragma unroll
  for (int off = 32; off > 0; off >>= 1) v += __shfl_down(v, off, 64);
  if ((t & 63) == 0) part[t >> 6] = v;
  __syncthreads();
  if (t == 0) out[g] = part[0] + part[1] + part[2] + part[3] + (float)(en - st) * decb[0];
}

// ---------------- launch ----------------

extern "C" void kernel_launch(void* const* d_in, const int* in_sizes, int n_in,
                              void* d_out, int out_size, void* d_ws, size_t ws_size,
                              hipStream_t stream) {
  (void)in_sizes; (void)n_in; (void)out_size; (void)ws_size;
  const float* x     = (const float*)d_in[0];
  const float* pos   = (const float*)d_in[1];
  const int*   ei    = (const int*)d_in[2];
  const int*   batch = (const int*)d_in[3];
  const float* encW  = (const float*)d_in[4];
  const float* encb  = (const float*)d_in[5];
  const float* convW = (const float*)d_in[6];
  const float* convb = (const float*)d_in[7];
  const float* resW  = (const float*)d_in[8];
  const float* resb  = (const float*)d_in[9];
  const float* decW  = (const float*)d_in[10];
  const float* decb  = (const float*)d_in[11];
  float* out = (float*)d_out;

  const int* src = ei;       // edge_index[0]
  const int* dst = ei + NE;  // edge_index[1]

  // workspace layout (4-byte elems)
  float*          ws     = (float*)d_ws;
  float*          dinv   = ws;                          // [NPAD]
  int*            rowst  = (int*)(ws + NPAD);           // [NPAD]
  int*            rowen  = (int*)(ws + 2 * NPAD);       // [NPAD]
  int*            bcur   = (int*)(ws + 3 * NPAD);       // [1024]
  int*            gptr   = bcur + 1024;                 // [NG+1]
  float*          Xo     = (float*)(gptr + 512);        // [NPAD]
  int*            colp   = (int*)(Xo + NPAD);           // [NBKT*CAP] packed (src<<6)|dstLow
  int*            cols   = colp + NBKT * CAP;           // [NBKT*CAP] sorted src
  unsigned short* hWbf   = (unsigned short*)(cols + NBKT * CAP);      // [NPAD*64] bf16
  unsigned short* gsum   = hWbf + (size_t)NPAD * 64;                  // [NPAD*64] bf16
  float*          bufA   = (float*)(gsum + (size_t)NPAD * 64);        // [NN*NH]
  float*          bufB   = bufA + NN * NH;

  hipMemsetAsync(bcur, 0, 1024 * sizeof(int), stream);

  k_bin<<<(NE + 8191) / 8192, 256, 0, stream>>>(src, dst, bcur, colp);
  k_csr<<<NBKT, 256, 0, stream>>>(bcur, colp, cols, dinv, rowst, rowen, batch, gptr);

  k_encoder<<<(NN + 3) / 4, 256, 0, stream>>>(x, pos, encW, encb, bufA);

  float* aggIn = bufA;   // X0 for l=0; thereafter agg_{l-1}
  float* aggOut = bufB;
  for (int l = 0; l < 5; l++) {
    int last = (l == 4) ? 1 : 0;
    k_gemm_dual<<<NBKT, 256, 0, stream>>>(aggIn, gsum, convW, resW, convb, resb, dinv,
                                          hWbf, aggOut, l > 0 ? 1 : 0);
    k_gather<<<NN / 4, 256, 0, stream>>>(rowst, rowen, cols, hWbf, gsum,
                                         aggOut, dinv, decW, Xo, last);
    float* tmp = aggIn; aggIn = aggOut; aggOut = tmp;
  }
  k_pool<<<NG, 256, 0, stream>>>(Xo, gptr, decb, out);
}